// Round 2
// baseline (172.026 us; speedup 1.0000x reference)
//
#include <hip/hip_runtime.h>

#define B_ 64
#define L_ 1024
#define M_ 256
#define F_ 256

typedef unsigned int u32;

// Async 16B global->LDS (DMA, no VGPR round-trip). LDS dest is wave-uniform
// base + lane*16; global src is per-lane (so swizzle lives in the src addr).
__device__ __forceinline__ void async_cp16(const float* g, float* l) {
    __builtin_amdgcn_global_load_lds(
        (const __attribute__((address_space(1))) u32*)g,
        (__attribute__((address_space(3))) u32*)l,
        16, 0, 0);
}

// One block per l, 256 threads. Thread (tx,ty) owns an 8x8 (b,m) tile:
//   m = tx + 32*j, b = ty*8 + i. K tiled by 32, LDS double-buffered,
// staged via global_load_lds with pre-swizzled Q source addresses.
__launch_bounds__(256, 2)
__global__ void mq_fused_kernel(const float* __restrict__ patch,
                                const float* __restrict__ queue,
                                float* __restrict__ out) {
    const int l  = blockIdx.x;
    const int t  = threadIdx.x;
    const int tx = t & 31;
    const int ty = t >> 5;

    // 2 x (Q 32KB + P 8KB) = 80KB exactly -> 2 blocks/CU. sidx overlays Ql[0].
    __shared__ float Ql[2][256 * 32];   // [m][f] stride 32, chunk XOR-swizzled by (m&7)
    __shared__ float Pl[2][64 * 32];    // [b][f] stride 32 (reads are broadcast)

    const int lane = t & 63;
    const int w    = t >> 6;           // wave id 0..3
    const int lrow = lane >> 3;        // 0..7: row within an 8-row chunk
    const int lcq  = (lane & 7) ^ lrow; // pre-swizzled Q col-chunk (lrow&7==lrow)
    const int lcp  = lane & 7;

    // Per-lane global base addresses for the 10 staged chunks (1KB LDS each).
    // Q chunk c = w*8+k covers rows c*8..c*8+7; P chunk c = w*2+k.
    const float* qbase[8];
#pragma unroll
    for (int k = 0; k < 8; ++k)
        qbase[k] = queue + ((size_t)l * M_ + (w * 8 + k) * 8 + lrow) * F_ + lcq * 4;
    const float* pbase[2];
#pragma unroll
    for (int k = 0; k < 2; ++k)
        pbase[k] = patch + ((size_t)((w * 2 + k) * 8 + lrow) * L_ + l) * F_ + lcp * 4;

    float acc[8][8];
#pragma unroll
    for (int i = 0; i < 8; ++i)
#pragma unroll
        for (int j = 0; j < 8; ++j) acc[i][j] = 0.f;

    // Prologue: stage tile 0 into buffer 0.
#pragma unroll
    for (int k = 0; k < 8; ++k) async_cp16(qbase[k], &Ql[0][(w * 8 + k) * 256]);
#pragma unroll
    for (int k = 0; k < 2; ++k) async_cp16(pbase[k], &Pl[0][(w * 2 + k) * 256]);

    for (int ft = 0; ft < 8; ++ft) {
        // Barrier: implicit vmcnt(0) drains THIS tile's loads (they had the
        // whole previous compute phase in flight), and fences buffer reuse.
        __syncthreads();

        // Issue next tile's loads into the other buffer -> in flight across
        // the compute below.
        if (ft < 7) {
            const int nxt = (ft + 1) & 1;
            const int o   = (ft + 1) * 32;
#pragma unroll
            for (int k = 0; k < 8; ++k)
                async_cp16(qbase[k] + o, &Ql[nxt][(w * 8 + k) * 256]);
#pragma unroll
            for (int k = 0; k < 2; ++k)
                async_cp16(pbase[k] + o, &Pl[nxt][(w * 2 + k) * 256]);
        }

        const int cur = ft & 1;
#pragma unroll
        for (int f4 = 0; f4 < 8; ++f4) {
            float4 pr[8], qr[8];
#pragma unroll
            for (int i = 0; i < 8; ++i)
                pr[i] = *reinterpret_cast<const float4*>(
                    &Pl[cur][(ty * 8 + i) * 32 + f4 * 4]);
            const int qc = (f4 ^ (tx & 7)) * 4;   // (tx+32j)&7 == tx&7
#pragma unroll
            for (int j = 0; j < 8; ++j)
                qr[j] = *reinterpret_cast<const float4*>(
                    &Ql[cur][(tx + 32 * j) * 32 + qc]);
#pragma unroll
            for (int i = 0; i < 8; ++i)
#pragma unroll
                for (int j = 0; j < 8; ++j) {
                    acc[i][j] += pr[i].x * qr[j].x;
                    acc[i][j] += pr[i].y * qr[j].y;
                    acc[i][j] += pr[i].z * qr[j].z;
                    acc[i][j] += pr[i].w * qr[j].w;
                }
        }
    }

    // argmax over m per b (numpy first-occurrence tie-break). Final compute
    // used Ql[1]; sidx overlays Ql[0], which no wave reads after iter 6.
    int* sidx = (int*)&Ql[0][0];
#pragma unroll
    for (int i = 0; i < 8; ++i) {
        float bv = acc[i][0];
        int   bi = tx;
#pragma unroll
        for (int j = 1; j < 8; ++j) {
            const float cv = acc[i][j];
            const int   ci = tx + 32 * j;
            if (cv > bv) { bv = cv; bi = ci; }
        }
#pragma unroll
        for (int off = 16; off >= 1; off >>= 1) {
            const float ov = __shfl_xor(bv, off);
            const int   oi = __shfl_xor(bi, off);
            if (ov > bv || (ov == bv && oi < bi)) { bv = ov; bi = oi; }
        }
        if (tx == 0) sidx[ty * 8 + i] = bi;
    }
    __syncthreads();

    // gather: out[b][l][:] = queue[l][sidx[b]][:]
    const int cb = t >> 6;     // 0..3
    const int cc = t & 63;     // float4 index within the 256-float row
    for (int b0 = 0; b0 < 64; b0 += 4) {
        const int b  = b0 + cb;
        const int mi = sidx[b];
        const float4 v = *reinterpret_cast<const float4*>(
            &queue[((size_t)l * M_ + mi) * F_ + cc * 4]);
        *reinterpret_cast<float4*>(&out[((size_t)b * L_ + l) * F_ + cc * 4]) = v;
    }
}

extern "C" void kernel_launch(void* const* d_in, const int* in_sizes, int n_in,
                              void* d_out, int out_size, void* d_ws, size_t ws_size,
                              hipStream_t stream) {
    const float* patch = (const float*)d_in[0];
    const float* queue = (const float*)d_in[1];
    float* out = (float*)d_out;
    mq_fused_kernel<<<dim3(L_), dim3(256), 0, stream>>>(patch, queue, out);
}